// Round 1
// baseline (1419.424 us; speedup 1.0000x reference)
//
#include <hip/hip_runtime.h>
#include <hip/hip_bf16.h>
#include <math.h>

#define NTOK 16384
#define DM 1024
#define DFF 4096
#define NEXP 8
#define CAP 2560
#define RB 256   // router blocks

typedef __bf16 bf16;
typedef float f32x4 __attribute__((ext_vector_type(4)));
typedef bf16 bf16x8 __attribute__((ext_vector_type(8)));
typedef bf16 bf16x4 __attribute__((ext_vector_type(4)));

// ---------------- workspace layout (bytes) ----------------
#define OFF_W1T   0ull                         // E*F*D bf16 = 67108864
#define OFF_W2T   67108864ull                  // E*D*F bf16 = 67108864
#define OFF_X     134217728ull                 // E*CAP*D bf16 = 41943040
#define OFF_H     176160768ull                 // CAP*F bf16 = 20971520
#define OFF_PROBS 197132288ull                 // E*N f32 = 524288
#define OFF_IDX   197656576ull                 // E*CAP i32 = 81920
#define OFF_WTS   197738496ull                 // E*CAP f32 = 81920
#define OFF_ENT   197820416ull                 // RB f32
#define WS_NEEDED 197825536ull

// ---------------- transpose + convert fp32 -> bf16 ----------------
// in: (E, R, C) row-major fp32 ; out: (E, C, R) row-major bf16
__global__ void k_transpose_cvt(const float* __restrict__ src, bf16* __restrict__ dst,
                                int R, int C) {
  __shared__ float tile[64][65];
  int e = blockIdx.z;
  src += (size_t)e * R * C;
  dst += (size_t)e * R * C;
  int c0 = blockIdx.x * 64, r0 = blockIdx.y * 64;
  int tc = threadIdx.x & 63, tr = threadIdx.x >> 6;
#pragma unroll
  for (int i = 0; i < 16; i++) {
    int r = tr + i * 4;
    tile[r][tc] = src[(size_t)(r0 + r) * C + c0 + tc];
  }
  __syncthreads();
#pragma unroll
  for (int i = 0; i < 16; i++) {
    int cc = tr + i * 4;
    dst[(size_t)(c0 + cc) * R + r0 + tc] = (bf16)tile[tc][cc];
  }
}

// ---------------- router: logits -> softmax -> probsT + entropy partials ----------------
__global__ __launch_bounds__(256) void k_router(const float* __restrict__ hidden,
                                                const float* __restrict__ rw,
                                                float* __restrict__ probsT,
                                                float* __restrict__ entPart) {
  __shared__ float rws[DM * NEXP];
  __shared__ float went[4];
  for (int i = threadIdx.x; i < DM * NEXP; i += 256) rws[i] = rw[i];
  __syncthreads();
  int wvid = threadIdx.x >> 6, lane = threadIdx.x & 63;
  float entAcc = 0.f;
  for (int token = blockIdx.x * 4 + wvid; token < NTOK; token += RB * 4) {
    float acc[NEXP];
#pragma unroll
    for (int e = 0; e < NEXP; e++) acc[e] = 0.f;
    const float* hp = hidden + (size_t)token * DM;
    for (int d = lane; d < DM; d += 64) {
      float h = hp[d];
#pragma unroll
      for (int e = 0; e < NEXP; e++) acc[e] = fmaf(h, rws[d * NEXP + e], acc[e]);
    }
#pragma unroll
    for (int e = 0; e < NEXP; e++) {
      float v = acc[e];
#pragma unroll
      for (int s = 1; s < 64; s <<= 1) v += __shfl_xor(v, s);
      acc[e] = v;
    }
    float mx = acc[0];
#pragma unroll
    for (int e = 1; e < NEXP; e++) mx = fmaxf(mx, acc[e]);
    float p[NEXP], s = 0.f;
#pragma unroll
    for (int e = 0; e < NEXP; e++) { p[e] = expf(acc[e] - mx); s += p[e]; }
    float inv = 1.f / s;
    float ent = 0.f;
#pragma unroll
    for (int e = 0; e < NEXP; e++) { p[e] *= inv; ent += p[e] * logf(p[e] + 1e-8f); }
    if (lane < NEXP) probsT[(size_t)lane * NTOK + token] = p[lane];
    if (lane == 0) entAcc += ent;
  }
  if (lane == 0) went[wvid] = entAcc;
  __syncthreads();
  if (threadIdx.x == 0) entPart[blockIdx.x] = went[0] + went[1] + went[2] + went[3];
}

// ---------------- aux loss final reduce (deterministic) ----------------
__global__ void k_aux(const float* __restrict__ part, float* __restrict__ outAux) {
  __shared__ float s[RB];
  int t = threadIdx.x;
  s[t] = part[t];
  __syncthreads();
  for (int st = RB / 2; st > 0; st >>= 1) {
    if (t < st) s[t] += s[t + st];
    __syncthreads();
  }
  if (t == 0) outAux[0] = s[0] * (1.f / (float)NTOK);
}

// ---------------- exact top-k per expert (jax.lax.top_k set semantics) ----------------
__global__ __launch_bounds__(1024) void k_topk(const float* __restrict__ probsT,
                                               int* __restrict__ idx,
                                               float* __restrict__ wts) {
  int e = blockIdx.x;
  const float* row = probsT + (size_t)e * NTOK;
  int t = threadIdx.x;
  unsigned u[16];
#pragma unroll
  for (int j = 0; j < 16; j++) u[j] = __float_as_uint(row[j * 1024 + t]);
  __shared__ int wred[16];
  __shared__ int bc;
  __shared__ int cnt_gt, cnt_eq;
  __shared__ int eqbuf[2048];
  int lane = t & 63, wv = t >> 6;
  unsigned prefix = 0;
  for (int bit = 30; bit >= 0; bit--) {
    unsigned cand = prefix | (1u << bit);
    int c = 0;
#pragma unroll
    for (int j = 0; j < 16; j++) c += (u[j] >= cand) ? 1 : 0;
#pragma unroll
    for (int s = 1; s < 64; s <<= 1) c += __shfl_xor(c, s);
    if (lane == 0) wred[wv] = c;
    __syncthreads();
    if (t == 0) { int tot = 0; for (int k = 0; k < 16; k++) tot += wred[k]; bc = tot; }
    __syncthreads();
    if (bc >= CAP) prefix = cand;
  }
  unsigned vC = prefix;  // bit pattern of the CAP-th largest value
  if (t == 0) { cnt_gt = 0; cnt_eq = 0; }
  __syncthreads();
#pragma unroll
  for (int j = 0; j < 16; j++) {
    int i = j * 1024 + t;
    if (u[j] > vC) {
      int p = atomicAdd(&cnt_gt, 1);
      idx[e * CAP + p] = i;
      wts[e * CAP + p] = __uint_as_float(u[j]);
    } else if (u[j] == vC) {
      int p = atomicAdd(&cnt_eq, 1);
      if (p < 2048) eqbuf[p] = i;
    }
  }
  __syncthreads();
  int m = cnt_gt;
  int ne = cnt_eq > 2048 ? 2048 : cnt_eq;
  int needed = CAP - m;
  for (int j = t; j < ne; j += 1024) {
    int my = eqbuf[j];
    int rank = 0;
    for (int k = 0; k < ne; k++) rank += (eqbuf[k] < my) ? 1 : 0;
    if (rank < needed) {
      idx[e * CAP + m + rank] = my;
      wts[e * CAP + m + rank] = __uint_as_float(vC);
    }
  }
}

// ---------------- gather selected tokens -> bf16 ----------------
__global__ void k_gather(const float* __restrict__ hidden, const int* __restrict__ idx,
                         bf16* __restrict__ X) {
  int ec = blockIdx.x;  // e*CAP + c
  int token = idx[ec];
  const float4* src = (const float4*)(hidden + (size_t)token * DM);
  bf16* dstrow = X + (size_t)ec * DM;
  int t = threadIdx.x;
  float4 v = src[t];
  bf16x4 o = {(bf16)v.x, (bf16)v.y, (bf16)v.z, (bf16)v.w};
  *(bf16x4*)(dstrow + t * 4) = o;
}

// ---------------- tiled bf16 MFMA GEMM ----------------
// A: (M, KDIM) row-major; Bt: (NN, KDIM) row-major (i.e. B transposed)
// EPILOGUE 0: H[row, col] = bf16(gelu_erf(acc))   (H stride NNtotal)
// EPILOGUE 1: out[idx[row], col] += wts[row] * acc (out stride DM)
template <int KDIM, int EPILOGUE>
__global__ __launch_bounds__(256) void k_gemm(const bf16* __restrict__ A,
                                              const bf16* __restrict__ Bt,
                                              bf16* __restrict__ H,
                                              const int* __restrict__ idx,
                                              const float* __restrict__ wts,
                                              float* __restrict__ out,
                                              int NNtotal) {
  __shared__ bf16 As[128 * 72];
  __shared__ bf16 Bs[128 * 72];
  int m0 = blockIdx.x * 128, n0 = blockIdx.y * 128;
  int t = threadIdx.x;
  int lane = t & 63;
  int wv = t >> 6, wm = wv >> 1, wn = wv & 1;
  f32x4 acc[4][4];
#pragma unroll
  for (int m = 0; m < 4; m++)
#pragma unroll
    for (int n = 0; n < 4; n++) acc[m][n] = (f32x4){0.f, 0.f, 0.f, 0.f};

  int srow = t >> 1, sseg = (t & 1) * 32;
  const bf16* gA = A + (size_t)(m0 + srow) * KDIM + sseg;
  const bf16* gB = Bt + (size_t)(n0 + srow) * KDIM + sseg;
  uint4* lA = (uint4*)(As + srow * 72 + sseg);
  uint4* lB = (uint4*)(Bs + srow * 72 + sseg);

  for (int kt = 0; kt < KDIM; kt += 64) {
    const uint4* ga4 = (const uint4*)(gA + kt);
    const uint4* gb4 = (const uint4*)(gB + kt);
#pragma unroll
    for (int j = 0; j < 4; j++) lA[j] = ga4[j];
#pragma unroll
    for (int j = 0; j < 4; j++) lB[j] = gb4[j];
    __syncthreads();
#pragma unroll
    for (int kk = 0; kk < 2; kk++) {
      int kb = kk * 32 + (lane >> 4) * 8;
      bf16x8 af[4], bfr[4];
#pragma unroll
      for (int m = 0; m < 4; m++)
        af[m] = *(const bf16x8*)(As + (wm * 64 + m * 16 + (lane & 15)) * 72 + kb);
#pragma unroll
      for (int n = 0; n < 4; n++)
        bfr[n] = *(const bf16x8*)(Bs + (wn * 64 + n * 16 + (lane & 15)) * 72 + kb);
#pragma unroll
      for (int m = 0; m < 4; m++)
#pragma unroll
        for (int n = 0; n < 4; n++)
          acc[m][n] = __builtin_amdgcn_mfma_f32_16x16x32_bf16(af[m], bfr[n], acc[m][n], 0, 0, 0);
    }
    __syncthreads();
  }

  int cl = lane & 15, rg = (lane >> 4) * 4;
  if (EPILOGUE == 0) {
#pragma unroll
    for (int m = 0; m < 4; m++) {
      int rowg = m0 + wm * 64 + m * 16 + rg;
#pragma unroll
      for (int n = 0; n < 4; n++) {
        int col = n0 + wn * 64 + n * 16 + cl;
#pragma unroll
        for (int r = 0; r < 4; r++) {
          float x = acc[m][n][r];
          float g = 0.5f * x * (1.f + erff(x * 0.70710678118654752f));
          H[(size_t)(rowg + r) * NNtotal + col] = (bf16)g;
        }
      }
    }
  } else {
#pragma unroll
    for (int m = 0; m < 4; m++) {
      int rowg = m0 + wm * 64 + m * 16 + rg;
#pragma unroll
      for (int r = 0; r < 4; r++) {
        int c = rowg + r;
        int token = idx[c];
        float w = wts[c];
        float* op = out + (size_t)token * DM + n0 + wn * 64 + cl;
#pragma unroll
        for (int n = 0; n < 4; n++) op[n * 16] += w * acc[m][n][r];
      }
    }
  }
}

extern "C" void kernel_launch(void* const* d_in, const int* in_sizes, int n_in,
                              void* d_out, int out_size, void* d_ws, size_t ws_size,
                              hipStream_t stream) {
  const float* hidden = (const float*)d_in[0];
  const float* router_w = (const float*)d_in[1];
  const float* W1 = (const float*)d_in[2];
  const float* W2 = (const float*)d_in[3];
  float* out = (float*)d_out;
  if (ws_size < WS_NEEDED) return;

  char* ws = (char*)d_ws;
  bf16* W1T = (bf16*)(ws + OFF_W1T);
  bf16* W2T = (bf16*)(ws + OFF_W2T);
  bf16* Xall = (bf16*)(ws + OFF_X);
  bf16* Hbuf = (bf16*)(ws + OFF_H);
  float* probsT = (float*)(ws + OFF_PROBS);
  int* idxb = (int*)(ws + OFF_IDX);
  float* wtsb = (float*)(ws + OFF_WTS);
  float* entPart = (float*)(ws + OFF_ENT);

  hipMemsetAsync(d_out, 0, (size_t)out_size * sizeof(float), stream);

  // W1 (E, D, F) -> W1T (E, F, D) ; W2 (E, F, D=DM? no: (E, F, D)) -> W2T (E, D, F)
  k_transpose_cvt<<<dim3(DFF / 64, DM / 64, NEXP), 256, 0, stream>>>(W1, W1T, DM, DFF);
  k_transpose_cvt<<<dim3(DM / 64, DFF / 64, NEXP), 256, 0, stream>>>(W2, W2T, DFF, DM);

  k_router<<<RB, 256, 0, stream>>>(hidden, router_w, probsT, entPart);
  k_aux<<<1, RB, 0, stream>>>(entPart, out + (size_t)NTOK * DM);
  k_topk<<<NEXP, 1024, 0, stream>>>(probsT, idxb, wtsb);
  k_gather<<<NEXP * CAP, 256, 0, stream>>>(hidden, idxb, Xall);

  for (int e = 0; e < NEXP; e++) {
    k_gemm<DM, 0><<<dim3(CAP / 128, DFF / 128), 256, 0, stream>>>(
        Xall + (size_t)e * CAP * DM, W1T + (size_t)e * DFF * DM, Hbuf,
        nullptr, nullptr, nullptr, DFF);
    k_gemm<DFF, 1><<<dim3(CAP / 128, DM / 128), 256, 0, stream>>>(
        Hbuf, W2T + (size_t)e * DM * DFF, nullptr,
        idxb + e * CAP, wtsb + e * CAP, out, DM);
  }
}

// Round 2
// 800.905 us; speedup vs baseline: 1.7723x; 1.7723x over previous
//
#include <hip/hip_runtime.h>
#include <hip/hip_bf16.h>
#include <math.h>

#define NTOK 16384
#define DM 1024
#define DFF 4096
#define NEXP 8
#define CAP 2560

typedef __bf16 bf16;
typedef float f32x4 __attribute__((ext_vector_type(4)));
typedef bf16 bf16x8 __attribute__((ext_vector_type(8)));
typedef bf16 bf16x4 __attribute__((ext_vector_type(4)));

// ---------------- workspace layout (bytes) ----------------
#define OFF_PROBS 0ull                 // E*N f32          = 524288
#define OFF_IDX   524288ull            // E*CAP i32        = 81920
#define OFF_WTS   606208ull            // E*CAP f32        = 81920
#define OFF_W1T   688128ull            // E*F*D bf16       = 67108864
#define OFF_W2T   67796992ull          // E*D*F bf16       = 67108864
#define OFF_X     134905856ull         // E*CAP*D bf16     = 41943040
#define OFF_ENT   OFF_X                // 4096 f32 (overlay: dead before gather writes X)
#define OFF_H     176848896ull         // serial: CAP*F bf16 = 20971520 ; fused: E*CAP*F bf16
#define WS_MIN    197820416ull
#define WS_FUSED  344621056ull

__device__ __forceinline__ void gl16(const bf16* g, bf16* l) {
  __builtin_amdgcn_global_load_lds((const __attribute__((address_space(1))) void*)g,
                                   (__attribute__((address_space(3))) void*)l, 16, 0, 0);
}

__device__ __forceinline__ float gelu_f(float x) {
  // x * sigmoid(2*sqrt(2/pi)*(x + 0.044715 x^3)) == tanh-approx GELU; |err vs erf| < 4e-4
  float u = 1.5957691216057308f * (x + 0.044715f * x * x * x);
  return x / (1.f + __expf(-u));
}

// ---------------- transpose + convert fp32 -> bf16 ----------------
__global__ __launch_bounds__(256) void k_transpose_cvt(const float* __restrict__ src,
                                                       bf16* __restrict__ dst, int R, int C) {
  __shared__ float tile[64][69];
  int e = blockIdx.z;
  src += (size_t)e * R * C;
  dst += (size_t)e * R * C;
  int c0 = blockIdx.x * 64, r0 = blockIdx.y * 64;
  int t = threadIdx.x;
  int tr = t >> 4, tc4 = (t & 15) * 4;
#pragma unroll
  for (int i = 0; i < 4; i++) {
    int r = tr + i * 16;
    float4 v = *(const float4*)(src + (size_t)(r0 + r) * C + c0 + tc4);
    tile[r][tc4] = v.x; tile[r][tc4 + 1] = v.y; tile[r][tc4 + 2] = v.z; tile[r][tc4 + 3] = v.w;
  }
  __syncthreads();
#pragma unroll
  for (int i = 0; i < 4; i++) {
    int orr = tr + i * 16;  // output row = source column
    bf16x4 o = {(bf16)tile[tc4][orr], (bf16)tile[tc4 + 1][orr],
                (bf16)tile[tc4 + 2][orr], (bf16)tile[tc4 + 3][orr]};
    *(bf16x4*)(dst + (size_t)(c0 + orr) * R + r0 + tc4) = o;
  }
}

// ---------------- router: one token per wave; fp-order identical to round 1 ----------------
__global__ __launch_bounds__(256) void k_router(const float* __restrict__ hidden,
                                                const float* __restrict__ rw,
                                                float* __restrict__ probsT,
                                                float* __restrict__ entPart) {
  __shared__ float went[4];
  int wv = threadIdx.x >> 6, lane = threadIdx.x & 63;
  int token = blockIdx.x * 4 + wv;
  float acc[NEXP];
#pragma unroll
  for (int e = 0; e < NEXP; e++) acc[e] = 0.f;
  const float* hp = hidden + (size_t)token * DM;
  for (int d = lane; d < DM; d += 64) {
    float h = hp[d];
#pragma unroll
    for (int e = 0; e < NEXP; e++) acc[e] = fmaf(h, rw[d * NEXP + e], acc[e]);
  }
#pragma unroll
  for (int e = 0; e < NEXP; e++) {
    float v = acc[e];
#pragma unroll
    for (int s = 1; s < 64; s <<= 1) v += __shfl_xor(v, s);
    acc[e] = v;
  }
  float mx = acc[0];
#pragma unroll
  for (int e = 1; e < NEXP; e++) mx = fmaxf(mx, acc[e]);
  float p[NEXP], s = 0.f;
#pragma unroll
  for (int e = 0; e < NEXP; e++) { p[e] = expf(acc[e] - mx); s += p[e]; }
  float inv = 1.f / s;
  float ent = 0.f;
#pragma unroll
  for (int e = 0; e < NEXP; e++) { p[e] *= inv; ent += p[e] * logf(p[e] + 1e-8f); }
  if (lane < NEXP) probsT[(size_t)lane * NTOK + token] = p[lane];
  if (lane == 0) went[wv] = ent;
  __syncthreads();
  if (threadIdx.x == 0) entPart[blockIdx.x] = went[0] + went[1] + went[2] + went[3];
}

// ---------------- aux loss final reduce (deterministic fixed order) ----------------
__global__ __launch_bounds__(256) void k_aux(const float* __restrict__ part, float* __restrict__ outAux) {
  __shared__ float s[256];
  int t = threadIdx.x;
  float v = 0.f;
#pragma unroll
  for (int i = 0; i < 16; i++) v += part[i * 256 + t];
  s[t] = v;
  __syncthreads();
  for (int st = 128; st > 0; st >>= 1) {
    if (t < st) s[t] += s[t + st];
    __syncthreads();
  }
  if (t == 0) outAux[0] = s[0] * (1.f / (float)NTOK);
}

// ---------------- exact top-k per expert ----------------
__global__ __launch_bounds__(1024) void k_topk(const float* __restrict__ probsT,
                                               int* __restrict__ idx,
                                               float* __restrict__ wts) {
  int e = blockIdx.x;
  const float* row = probsT + (size_t)e * NTOK;
  int t = threadIdx.x;
  unsigned u[16];
#pragma unroll
  for (int j = 0; j < 16; j++) u[j] = __float_as_uint(row[j * 1024 + t]);
  __shared__ int wred[16];
  __shared__ int bc;
  __shared__ int cnt_gt, cnt_eq;
  __shared__ int eqbuf[2048];
  int lane = t & 63, wv = t >> 6;
  unsigned prefix = 0;
  for (int bit = 30; bit >= 0; bit--) {
    unsigned cand = prefix | (1u << bit);
    int c = 0;
#pragma unroll
    for (int j = 0; j < 16; j++) c += (u[j] >= cand) ? 1 : 0;
#pragma unroll
    for (int s = 1; s < 64; s <<= 1) c += __shfl_xor(c, s);
    if (lane == 0) wred[wv] = c;
    __syncthreads();
    if (t == 0) { int tot = 0; for (int k = 0; k < 16; k++) tot += wred[k]; bc = tot; }
    __syncthreads();
    if (bc >= CAP) prefix = cand;
  }
  unsigned vC = prefix;
  if (t == 0) { cnt_gt = 0; cnt_eq = 0; }
  __syncthreads();
#pragma unroll
  for (int j = 0; j < 16; j++) {
    int i = j * 1024 + t;
    if (u[j] > vC) {
      int p = atomicAdd(&cnt_gt, 1);
      idx[e * CAP + p] = i;
      wts[e * CAP + p] = __uint_as_float(u[j]);
    } else if (u[j] == vC) {
      int p = atomicAdd(&cnt_eq, 1);
      if (p < 2048) eqbuf[p] = i;
    }
  }
  __syncthreads();
  int m = cnt_gt;
  int ne = cnt_eq > 2048 ? 2048 : cnt_eq;
  int needed = CAP - m;
  for (int j = t; j < ne; j += 1024) {
    int my = eqbuf[j];
    int rank = 0;
    for (int k = 0; k < ne; k++) rank += (eqbuf[k] < my) ? 1 : 0;
    if (rank < needed) {
      idx[e * CAP + m + rank] = my;
      wts[e * CAP + m + rank] = __uint_as_float(vC);
    }
  }
}

// ---------------- gather selected tokens -> bf16 ----------------
__global__ void k_gather(const float* __restrict__ hidden, const int* __restrict__ idx,
                         bf16* __restrict__ X) {
  int ec = blockIdx.x;
  int token = idx[ec];
  const float4* src = (const float4*)(hidden + (size_t)token * DM);
  bf16* dstrow = X + (size_t)ec * DM;
  int t = threadIdx.x;
  float4 v = src[t];
  bf16x4 o = {(bf16)v.x, (bf16)v.y, (bf16)v.z, (bf16)v.w};
  *(bf16x4*)(dstrow + t * 4) = o;
}

// ---------------- m97-style bf16 MFMA GEMM (global_load_lds staging) ----------------
template <int KD, int EPI>
__global__ __launch_bounds__(256) void k_gemm(const bf16* __restrict__ A,
                                              const bf16* __restrict__ Bt,
                                              bf16* __restrict__ H,
                                              const int* __restrict__ idx,
                                              const float* __restrict__ wts,
                                              float* __restrict__ out,
                                              size_t strA, size_t strB, size_t strH) {
  __shared__ bf16 As[128 * 64];
  __shared__ bf16 Bs[128 * 64];
  int e = blockIdx.z;
  A += (size_t)e * strA;
  Bt += (size_t)e * strB;
  int m0 = blockIdx.x * 128, n0 = blockIdx.y * 128;
  int t = threadIdx.x, lane = t & 63;
  int wv = t >> 6, wm = wv >> 1, wn = wv & 1;
  f32x4 acc[4][4];
#pragma unroll
  for (int m = 0; m < 4; m++)
#pragma unroll
    for (int n = 0; n < 4; n++) acc[m][n] = (f32x4){0.f, 0.f, 0.f, 0.f};

  // staging: chunk ch = wv*4+j covers rows ch*8..ch*8+7 (linear 1KB), lane gives 16B at lane*16
  const bf16* gA0 = A + (size_t)(m0 + wv * 32 + (lane >> 3)) * KD + (lane & 7) * 8;
  const bf16* gB0 = Bt + (size_t)(n0 + wv * 32 + (lane >> 3)) * KD + (lane & 7) * 8;
  bf16* lA0 = As + wv * 2048 + lane * 8;
  bf16* lB0 = Bs + wv * 2048 + lane * 8;

  for (int kt = 0; kt < KD; kt += 64) {
#pragma unroll
    for (int j = 0; j < 4; j++) {
      gl16(gA0 + (size_t)j * 8 * KD + kt, lA0 + j * 512);
      gl16(gB0 + (size_t)j * 8 * KD + kt, lB0 + j * 512);
    }
    __syncthreads();
#pragma unroll
    for (int kk = 0; kk < 2; kk++) {
      int kb = kk * 32 + (lane >> 4) * 8;
      bf16x8 af[4], bfm[4];
#pragma unroll
      for (int m = 0; m < 4; m++)
        af[m] = *(const bf16x8*)(As + (wm * 64 + m * 16 + (lane & 15)) * 64 + kb);
#pragma unroll
      for (int n = 0; n < 4; n++)
        bfm[n] = *(const bf16x8*)(Bs + (wn * 64 + n * 16 + (lane & 15)) * 64 + kb);
#pragma unroll
      for (int m = 0; m < 4; m++)
#pragma unroll
        for (int n = 0; n < 4; n++)
          acc[m][n] = __builtin_amdgcn_mfma_f32_16x16x32_bf16(af[m], bfm[n], acc[m][n], 0, 0, 0);
    }
    __syncthreads();
  }

  int cl = lane & 15, rg = (lane >> 4) * 4;
  if (EPI == 0) {
    bf16* He = H + (size_t)e * strH;
#pragma unroll
    for (int m = 0; m < 4; m++) {
      int rowg = m0 + wm * 64 + m * 16 + rg;
#pragma unroll
      for (int n = 0; n < 4; n++) {
        int col = n0 + wn * 64 + n * 16 + cl;
#pragma unroll
        for (int r = 0; r < 4; r++)
          He[(size_t)(rowg + r) * DFF + col] = (bf16)gelu_f(acc[m][n][r]);
      }
    }
  } else {
    const int* idxE = idx + (size_t)e * CAP;
    const float* wtsE = wts + (size_t)e * CAP;
#pragma unroll
    for (int m = 0; m < 4; m++) {
      int rowg = m0 + wm * 64 + m * 16 + rg;
#pragma unroll
      for (int r = 0; r < 4; r++) {
        int c = rowg + r;
        int token = idxE[c];
        float w = wtsE[c];
        float* op = out + (size_t)token * DM + n0 + wn * 64 + cl;
#pragma unroll
        for (int n = 0; n < 4; n++) atomicAdd(op + n * 16, w * acc[m][n][r]);
      }
    }
  }
}

extern "C" void kernel_launch(void* const* d_in, const int* in_sizes, int n_in,
                              void* d_out, int out_size, void* d_ws, size_t ws_size,
                              hipStream_t stream) {
  const float* hidden = (const float*)d_in[0];
  const float* router_w = (const float*)d_in[1];
  const float* W1 = (const float*)d_in[2];
  const float* W2 = (const float*)d_in[3];
  float* out = (float*)d_out;
  if (ws_size < WS_MIN) return;

  char* ws = (char*)d_ws;
  float* probsT = (float*)(ws + OFF_PROBS);
  int* idxb = (int*)(ws + OFF_IDX);
  float* wtsb = (float*)(ws + OFF_WTS);
  bf16* W1T = (bf16*)(ws + OFF_W1T);
  bf16* W2T = (bf16*)(ws + OFF_W2T);
  bf16* Xall = (bf16*)(ws + OFF_X);
  float* entPart = (float*)(ws + OFF_ENT);
  bf16* Hbuf = (bf16*)(ws + OFF_H);

  hipMemsetAsync(d_out, 0, (size_t)out_size * sizeof(float), stream);

  k_transpose_cvt<<<dim3(DFF / 64, DM / 64, NEXP), 256, 0, stream>>>(W1, W1T, DM, DFF);
  k_transpose_cvt<<<dim3(DM / 64, DFF / 64, NEXP), 256, 0, stream>>>(W2, W2T, DFF, DM);

  k_router<<<NTOK / 4, 256, 0, stream>>>(hidden, router_w, probsT, entPart);
  k_aux<<<1, 256, 0, stream>>>(entPart, out + (size_t)NTOK * DM);
  k_topk<<<NEXP, 1024, 0, stream>>>(probsT, idxb, wtsb);
  k_gather<<<NEXP * CAP, 256, 0, stream>>>(hidden, idxb, Xall);

  if (ws_size >= WS_FUSED) {
    k_gemm<DM, 0><<<dim3(CAP / 128, DFF / 128, NEXP), 256, 0, stream>>>(
        Xall, W1T, Hbuf, nullptr, nullptr, nullptr,
        (size_t)CAP * DM, (size_t)DFF * DM, (size_t)CAP * DFF);
    k_gemm<DFF, 1><<<dim3(CAP / 128, DM / 128, NEXP), 256, 0, stream>>>(
        Hbuf, W2T, nullptr, idxb, wtsb, out,
        (size_t)CAP * DFF, (size_t)DM * DFF, 0);
  } else {
    for (int e = 0; e < NEXP; e++) {
      k_gemm<DM, 0><<<dim3(CAP / 128, DFF / 128, 1), 256, 0, stream>>>(
          Xall + (size_t)e * CAP * DM, W1T + (size_t)e * DFF * DM, Hbuf,
          nullptr, nullptr, nullptr, 0, 0, 0);
      k_gemm<DFF, 1><<<dim3(CAP / 128, DM / 128, 1), 256, 0, stream>>>(
          Hbuf, W2T + (size_t)e * DM * DFF, nullptr,
          idxb + e * CAP, wtsb + e * CAP, out, 0, 0, 0);
    }
  }
}

// Round 3
// 667.039 us; speedup vs baseline: 2.1279x; 1.2007x over previous
//
#include <hip/hip_runtime.h>
#include <hip/hip_bf16.h>
#include <math.h>

#define NTOK 16384
#define DM 1024
#define DFF 4096
#define NEXP 8
#define CAP 2560

typedef __bf16 bf16;
typedef float f32x4 __attribute__((ext_vector_type(4)));
typedef bf16 bf16x8 __attribute__((ext_vector_type(8)));
typedef bf16 bf16x4 __attribute__((ext_vector_type(4)));

// ---------------- workspace layout (bytes) ----------------
#define OFF_PROBS 0ull                 // E*N f32          = 524288
#define OFF_IDX   524288ull            // E*CAP i32        = 81920
#define OFF_WTS   606208ull            // E*CAP f32        = 81920
#define OFF_W1T   688128ull            // E*F*D bf16       = 67108864
#define OFF_W2T   67796992ull          // E*D*F bf16       = 67108864
#define OFF_X     134905856ull         // E*CAP*D bf16     = 41943040
#define OFF_ENT   OFF_X                // 4096 f32 (overlay: dead before gather writes X)
#define OFF_H     176848896ull         // fused: E*CAP*F bf16 = 167772160
#define WS_MIN    197820416ull
#define WS_FUSED  344621056ull

#define BAR() do { asm volatile("" ::: "memory"); __builtin_amdgcn_s_barrier(); asm volatile("" ::: "memory"); } while (0)

__device__ __forceinline__ void gl16(const bf16* g, const bf16* l) {
  __builtin_amdgcn_global_load_lds((const __attribute__((address_space(1))) void*)g,
                                   (__attribute__((address_space(3))) void*)l, 16, 0, 0);
}

__device__ __forceinline__ float gelu_f(float x) {
  float u = 1.5957691216057308f * (x + 0.044715f * x * x * x);
  return x / (1.f + __expf(-u));
}

// ---------------- transpose + convert fp32 -> bf16 ----------------
__global__ __launch_bounds__(256) void k_transpose_cvt(const float* __restrict__ src,
                                                       bf16* __restrict__ dst, int R, int C) {
  __shared__ float tile[64][69];
  int e = blockIdx.z;
  src += (size_t)e * R * C;
  dst += (size_t)e * R * C;
  int c0 = blockIdx.x * 64, r0 = blockIdx.y * 64;
  int t = threadIdx.x;
  int tr = t >> 4, tc4 = (t & 15) * 4;
#pragma unroll
  for (int i = 0; i < 4; i++) {
    int r = tr + i * 16;
    float4 v = *(const float4*)(src + (size_t)(r0 + r) * C + c0 + tc4);
    tile[r][tc4] = v.x; tile[r][tc4 + 1] = v.y; tile[r][tc4 + 2] = v.z; tile[r][tc4 + 3] = v.w;
  }
  __syncthreads();
#pragma unroll
  for (int i = 0; i < 4; i++) {
    int orr = tr + i * 16;
    bf16x4 o = {(bf16)tile[tc4][orr], (bf16)tile[tc4 + 1][orr],
                (bf16)tile[tc4 + 2][orr], (bf16)tile[tc4 + 3][orr]};
    *(bf16x4*)(dst + (size_t)(c0 + orr) * R + r0 + tc4) = o;
  }
}

// ---------------- router ----------------
__global__ __launch_bounds__(256) void k_router(const float* __restrict__ hidden,
                                                const float* __restrict__ rw,
                                                float* __restrict__ probsT,
                                                float* __restrict__ entPart) {
  __shared__ float went[4];
  int wv = threadIdx.x >> 6, lane = threadIdx.x & 63;
  int token = blockIdx.x * 4 + wv;
  float acc[NEXP];
#pragma unroll
  for (int e = 0; e < NEXP; e++) acc[e] = 0.f;
  const float* hp = hidden + (size_t)token * DM;
  for (int d = lane; d < DM; d += 64) {
    float h = hp[d];
#pragma unroll
    for (int e = 0; e < NEXP; e++) acc[e] = fmaf(h, rw[d * NEXP + e], acc[e]);
  }
#pragma unroll
  for (int e = 0; e < NEXP; e++) {
    float v = acc[e];
#pragma unroll
    for (int s = 1; s < 64; s <<= 1) v += __shfl_xor(v, s);
    acc[e] = v;
  }
  float mx = acc[0];
#pragma unroll
  for (int e = 1; e < NEXP; e++) mx = fmaxf(mx, acc[e]);
  float p[NEXP], s = 0.f;
#pragma unroll
  for (int e = 0; e < NEXP; e++) { p[e] = expf(acc[e] - mx); s += p[e]; }
  float inv = 1.f / s;
  float ent = 0.f;
#pragma unroll
  for (int e = 0; e < NEXP; e++) { p[e] *= inv; ent += p[e] * logf(p[e] + 1e-8f); }
  if (lane < NEXP) probsT[(size_t)lane * NTOK + token] = p[lane];
  if (lane == 0) went[wv] = ent;
  __syncthreads();
  if (threadIdx.x == 0) entPart[blockIdx.x] = went[0] + went[1] + went[2] + went[3];
}

__global__ __launch_bounds__(256) void k_aux(const float* __restrict__ part, float* __restrict__ outAux) {
  __shared__ float s[256];
  int t = threadIdx.x;
  float v = 0.f;
#pragma unroll
  for (int i = 0; i < 16; i++) v += part[i * 256 + t];
  s[t] = v;
  __syncthreads();
  for (int st = 128; st > 0; st >>= 1) {
    if (t < st) s[t] += s[t + st];
    __syncthreads();
  }
  if (t == 0) outAux[0] = s[0] * (1.f / (float)NTOK);
}

// ---------------- exact top-k per expert ----------------
__global__ __launch_bounds__(1024) void k_topk(const float* __restrict__ probsT,
                                               int* __restrict__ idx,
                                               float* __restrict__ wts) {
  int e = blockIdx.x;
  const float* row = probsT + (size_t)e * NTOK;
  int t = threadIdx.x;
  unsigned u[16];
#pragma unroll
  for (int j = 0; j < 16; j++) u[j] = __float_as_uint(row[j * 1024 + t]);
  __shared__ int wred[16];
  __shared__ int bc;
  __shared__ int cnt_gt, cnt_eq;
  __shared__ int eqbuf[2048];
  int lane = t & 63, wv = t >> 6;
  unsigned prefix = 0;
  for (int bit = 30; bit >= 0; bit--) {
    unsigned cand = prefix | (1u << bit);
    int c = 0;
#pragma unroll
    for (int j = 0; j < 16; j++) c += (u[j] >= cand) ? 1 : 0;
#pragma unroll
    for (int s = 1; s < 64; s <<= 1) c += __shfl_xor(c, s);
    if (lane == 0) wred[wv] = c;
    __syncthreads();
    if (t == 0) { int tot = 0; for (int k = 0; k < 16; k++) tot += wred[k]; bc = tot; }
    __syncthreads();
    if (bc >= CAP) prefix = cand;
  }
  unsigned vC = prefix;
  if (t == 0) { cnt_gt = 0; cnt_eq = 0; }
  __syncthreads();
#pragma unroll
  for (int j = 0; j < 16; j++) {
    int i = j * 1024 + t;
    if (u[j] > vC) {
      int p = atomicAdd(&cnt_gt, 1);
      idx[e * CAP + p] = i;
      wts[e * CAP + p] = __uint_as_float(u[j]);
    } else if (u[j] == vC) {
      int p = atomicAdd(&cnt_eq, 1);
      if (p < 2048) eqbuf[p] = i;
    }
  }
  __syncthreads();
  int m = cnt_gt;
  int ne = cnt_eq > 2048 ? 2048 : cnt_eq;
  int needed = CAP - m;
  for (int j = t; j < ne; j += 1024) {
    int my = eqbuf[j];
    int rank = 0;
    for (int k = 0; k < ne; k++) rank += (eqbuf[k] < my) ? 1 : 0;
    if (rank < needed) {
      idx[e * CAP + m + rank] = my;
      wts[e * CAP + m + rank] = __uint_as_float(vC);
    }
  }
}

// ---------------- gather selected tokens -> bf16 ----------------
__global__ void k_gather(const float* __restrict__ hidden, const int* __restrict__ idx,
                         bf16* __restrict__ X) {
  int ec = blockIdx.x;
  int token = idx[ec];
  const float4* src = (const float4*)(hidden + (size_t)token * DM);
  bf16* dstrow = X + (size_t)ec * DM;
  int t = threadIdx.x;
  float4 v = src[t];
  bf16x4 o = {(bf16)v.x, (bf16)v.y, (bf16)v.z, (bf16)v.w};
  *(bf16x4*)(dstrow + t * 4) = o;
}

// ---------------- 256x256 8-phase bf16 MFMA GEMM ----------------
// EPI 0 (GEMM1): A=Xall(e), B=W1T(e), KD=DM,  NT=16, write H with gelu.
// EPI 1 (GEMM2): A=H(e),    B=W2T(e), KD=DFF, NT=32 per K-half (split-K=2), atomic scatter.
// LDS swizzle: phys 16B-slot = logical_slot ^ (row&7); global_load_lds sources are
// pre-swizzled per-lane ((lane&7)^(lane>>3)) so linear LDS dest receives swizzled layout.
template <int EPI>
__global__ __launch_bounds__(512, 2) void k_gemm256(
    const bf16* __restrict__ Ab, const bf16* __restrict__ Bb,
    bf16* __restrict__ Hb, const int* __restrict__ idxb, const float* __restrict__ wtsb,
    float* __restrict__ outb, int zOffset) {
  constexpr int KD  = (EPI == 0) ? DM : DFF;   // row stride (K) of A and B
  constexpr int NBX = 10;
  constexpr int NBY = (EPI == 0) ? 16 : 4;
  constexpr int NT  = (EPI == 0) ? 16 : 32;    // K-tiles of 64 per block

  __shared__ bf16 As[2][256 * 64];  // 64 KiB
  __shared__ bf16 Bs[2][256 * 64];  // 64 KiB

  int nwg = gridDim.x;
  int wg = (blockIdx.x & 7) * (nwg >> 3) + (blockIdx.x >> 3);  // XCD-chunked (nwg%8==0)
  int zl = wg / (NBX * NBY);
  int r = wg % (NBX * NBY);
  int by = r % NBY, bx = r / NBY;
  int z = zl + zOffset;
  int e, k0;
  const bf16 *A, *B;
  if constexpr (EPI == 0) {
    e = z; k0 = 0;
    A = Ab + (size_t)e * CAP * DM;
    B = Bb + (size_t)e * DFF * DM;
  } else {
    e = z >> 1; k0 = (z & 1) * (DFF / 2);
    A = Ab + (size_t)e * CAP * DFF;
    B = Bb + (size_t)e * DM * DFF;
  }
  int m0 = bx * 256, n0 = by * 256;

  int t = threadIdx.x, lane = t & 63, wv = t >> 6;
  int wm = wv >> 2, wn = wv & 3;
  int l3 = lane >> 3, l7 = lane & 7;
  int cswz = (l7 ^ l3) * 8;  // pre-swizzled global col offset (elems)

  // stage one half-tile (16 KiB) : 8 waves x 2 chunks x 1KiB(8 rows)
  // half 0: A rows for m-frags 0-3 ; half 1: B rows n-frags 0-1
  // half 2: B rows n-frags 2-3     ; half 3: A rows m-frags 4-7
  auto stage = [&](int half, int ktE, int buf) {
#pragma unroll
    for (int j = 0; j < 2; ++j) {
      int u = wv * 2 + j;
      int rb;
      const bf16* G;
      bf16* L;
      if (half == 0) { rb = u * 8 + (u >> 3) * 64;       G = A + (size_t)(m0 + rb + l3) * KD; L = &As[buf][rb * 64]; }
      else if (half == 3) { rb = 64 + u * 8 + (u >> 3) * 64; G = A + (size_t)(m0 + rb + l3) * KD; L = &As[buf][rb * 64]; }
      else if (half == 1) { rb = (u >> 2) * 64 + (u & 3) * 8;      G = B + (size_t)(n0 + rb + l3) * KD; L = &Bs[buf][rb * 64]; }
      else { rb = (u >> 2) * 64 + 32 + (u & 3) * 8; G = B + (size_t)(n0 + rb + l3) * KD; L = &Bs[buf][rb * 64]; }
      gl16(G + ktE + cswz, L + lane * 8);
    }
  };

  auto rdA = [&](const bf16* base, int q, int i, int kk) -> bf16x8 {
    int rr = wm * 128 + (q * 4 + i) * 16 + (lane & 15);
    int slot = (kk * 4 + (lane >> 4)) ^ l7;
    return *(const bf16x8*)((const char*)base + rr * 128 + slot * 16);
  };
  auto rdB = [&](const bf16* base, int h, int i, int kk) -> bf16x8 {
    int rr = wn * 64 + (h * 2 + i) * 16 + (lane & 15);
    int slot = (kk * 4 + (lane >> 4)) ^ l7;
    return *(const bf16x8*)((const char*)base + rr * 128 + slot * 16);
  };

  f32x4 acc[8][4];
#pragma unroll
  for (int m = 0; m < 8; m++)
#pragma unroll
    for (int n = 0; n < 4; n++) acc[m][n] = (f32x4){0.f, 0.f, 0.f, 0.f};
  bf16x8 aF[4][2], bF0[2][2], bF1[2][2];

  // prologue: tile 0 -> buf0, order A0,B0,B1,A1 (8 loads/wave outstanding)
  stage(0, k0, 0); stage(1, k0, 0); stage(2, k0, 0); stage(3, k0, 0);
  asm volatile("s_waitcnt vmcnt(4)" ::: "memory");  // A0,B0 landed
  BAR();

  for (int kt = 0; kt < NT; ++kt) {
    int cur = kt & 1;
    int nxE = k0 + (kt + 1) * 64;
    bool nl = (kt < NT - 1);
    // ---- p0: rd A q0 + B h0 ; stage A0(next) ; mfma m0-3 x n0-1 ----
#pragma unroll
    for (int i = 0; i < 4; i++)
#pragma unroll
      for (int kk = 0; kk < 2; kk++) aF[i][kk] = rdA(As[cur], 0, i, kk);
#pragma unroll
    for (int i = 0; i < 2; i++)
#pragma unroll
      for (int kk = 0; kk < 2; kk++) bF0[i][kk] = rdB(Bs[cur], 0, i, kk);
    if (nl) stage(0, nxE, cur ^ 1);
    BAR();
    asm volatile("s_waitcnt lgkmcnt(0)" ::: "memory");
    __builtin_amdgcn_s_setprio(1);
#pragma unroll
    for (int i = 0; i < 4; i++)
#pragma unroll
      for (int j = 0; j < 2; j++)
#pragma unroll
        for (int kk = 0; kk < 2; kk++)
          acc[i][j] = __builtin_amdgcn_mfma_f32_16x16x32_bf16(aF[i][kk], bF0[j][kk], acc[i][j], 0, 0, 0);
    __builtin_amdgcn_s_setprio(0);
    if (nl) asm volatile("s_waitcnt vmcnt(4)" ::: "memory");   // B1(t) landed
    else    asm volatile("s_waitcnt vmcnt(2)" ::: "memory");
    BAR();
    // ---- p1: rd B h1 ; stage B0(next) ; mfma m0-3 x n2-3 ----
#pragma unroll
    for (int i = 0; i < 2; i++)
#pragma unroll
      for (int kk = 0; kk < 2; kk++) bF1[i][kk] = rdB(Bs[cur], 1, i, kk);
    if (nl) stage(1, nxE, cur ^ 1);
    BAR();
    asm volatile("s_waitcnt lgkmcnt(0)" ::: "memory");
    __builtin_amdgcn_s_setprio(1);
#pragma unroll
    for (int i = 0; i < 4; i++)
#pragma unroll
      for (int j = 0; j < 2; j++)
#pragma unroll
        for (int kk = 0; kk < 2; kk++)
          acc[i][2 + j] = __builtin_amdgcn_mfma_f32_16x16x32_bf16(aF[i][kk], bF1[j][kk], acc[i][2 + j], 0, 0, 0);
    __builtin_amdgcn_s_setprio(0);
    if (nl) asm volatile("s_waitcnt vmcnt(4)" ::: "memory");   // A1(t) landed
    else    asm volatile("s_waitcnt vmcnt(0)" ::: "memory");
    BAR();
    // ---- p2: rd A q1 ; stage B1(next) ; mfma m4-7 x n0-1 ----
#pragma unroll
    for (int i = 0; i < 4; i++)
#pragma unroll
      for (int kk = 0; kk < 2; kk++) aF[i][kk] = rdA(As[cur], 1, i, kk);
    if (nl) stage(2, nxE, cur ^ 1);
    BAR();
    asm volatile("s_waitcnt lgkmcnt(0)" ::: "memory");
    __builtin_amdgcn_s_setprio(1);
#pragma unroll
    for (int i = 0; i < 4; i++)
#pragma unroll
      for (int j = 0; j < 2; j++)
#pragma unroll
        for (int kk = 0; kk < 2; kk++)
          acc[4 + i][j] = __builtin_amdgcn_mfma_f32_16x16x32_bf16(aF[i][kk], bF0[j][kk], acc[4 + i][j], 0, 0, 0);
    __builtin_amdgcn_s_setprio(0);
    BAR();
    // ---- p3: stage A1(next) ; mfma m4-7 x n2-3 ----
    if (nl) stage(3, nxE, cur ^ 1);
    BAR();
    __builtin_amdgcn_s_setprio(1);
#pragma unroll
    for (int i = 0; i < 4; i++)
#pragma unroll
      for (int j = 0; j < 2; j++)
#pragma unroll
        for (int kk = 0; kk < 2; kk++)
          acc[4 + i][2 + j] = __builtin_amdgcn_mfma_f32_16x16x32_bf16(aF[i][kk], bF1[j][kk], acc[4 + i][2 + j], 0, 0, 0);
    __builtin_amdgcn_s_setprio(0);
    if (nl) asm volatile("s_waitcnt vmcnt(4)" ::: "memory");   // A0,B0(next) landed
    BAR();
  }

  int cl = lane & 15, rg = (lane >> 4) * 4;
  if constexpr (EPI == 0) {
    bf16* He = Hb + (size_t)e * CAP * DFF;
#pragma unroll
    for (int m = 0; m < 8; m++) {
      int rowg = m0 + wm * 128 + m * 16 + rg;
#pragma unroll
      for (int n = 0; n < 4; n++) {
        int col = n0 + wn * 64 + n * 16 + cl;
#pragma unroll
        for (int rr = 0; rr < 4; rr++)
          He[(size_t)(rowg + rr) * DFF + col] = (bf16)gelu_f(acc[m][n][rr]);
      }
    }
  } else {
    const int* idxE = idxb + e * CAP;
    const float* wtsE = wtsb + e * CAP;
#pragma unroll
    for (int m = 0; m < 8; m++) {
      int rowg = m0 + wm * 128 + m * 16 + rg;
#pragma unroll
      for (int rr = 0; rr < 4; rr++) {
        int c = rowg + rr;
        int token = idxE[c];
        float w = wtsE[c];
        float* op = outb + (size_t)token * DM + n0 + wn * 64 + cl;
#pragma unroll
        for (int n = 0; n < 4; n++) atomicAdd(op + n * 16, w * acc[m][n][rr]);
      }
    }
  }
}

extern "C" void kernel_launch(void* const* d_in, const int* in_sizes, int n_in,
                              void* d_out, int out_size, void* d_ws, size_t ws_size,
                              hipStream_t stream) {
  const float* hidden = (const float*)d_in[0];
  const float* router_w = (const float*)d_in[1];
  const float* W1 = (const float*)d_in[2];
  const float* W2 = (const float*)d_in[3];
  float* out = (float*)d_out;
  if (ws_size < WS_MIN) return;

  char* ws = (char*)d_ws;
  float* probsT = (float*)(ws + OFF_PROBS);
  int* idxb = (int*)(ws + OFF_IDX);
  float* wtsb = (float*)(ws + OFF_WTS);
  bf16* W1T = (bf16*)(ws + OFF_W1T);
  bf16* W2T = (bf16*)(ws + OFF_W2T);
  bf16* Xall = (bf16*)(ws + OFF_X);
  float* entPart = (float*)(ws + OFF_ENT);
  bf16* Hbuf = (bf16*)(ws + OFF_H);

  hipMemsetAsync(d_out, 0, (size_t)out_size * sizeof(float), stream);

  k_transpose_cvt<<<dim3(DFF / 64, DM / 64, NEXP), 256, 0, stream>>>(W1, W1T, DM, DFF);
  k_transpose_cvt<<<dim3(DM / 64, DFF / 64, NEXP), 256, 0, stream>>>(W2, W2T, DFF, DM);

  k_router<<<NTOK / 4, 256, 0, stream>>>(hidden, router_w, probsT, entPart);
  k_aux<<<1, 256, 0, stream>>>(entPart, out + (size_t)NTOK * DM);
  k_topk<<<NEXP, 1024, 0, stream>>>(probsT, idxb, wtsb);
  k_gather<<<NEXP * CAP, 256, 0, stream>>>(hidden, idxb, Xall);

  if (ws_size >= WS_FUSED) {
    k_gemm256<0><<<1280, 512, 0, stream>>>(Xall, W1T, Hbuf, nullptr, nullptr, nullptr, 0);
    k_gemm256<1><<<640, 512, 0, stream>>>(Hbuf, W2T, nullptr, idxb, wtsb, out, 0);
  } else {
    // serialized fallback: small H (CAP*DFF), adjust base so e-offset inside kernel cancels
    for (int e = 0; e < NEXP; e++) {
      bf16* Hadj = Hbuf - (size_t)e * CAP * DFF;
      k_gemm256<0><<<160, 512, 0, stream>>>(Xall, W1T, Hadj, nullptr, nullptr, nullptr, e);
      k_gemm256<1><<<80, 512, 0, stream>>>(Hadj, W2T, nullptr, idxb, wtsb, out, e * 2);
    }
  }
}